// Round 1
// 618.887 us; speedup vs baseline: 1.0307x; 1.0307x over previous
//
#include <hip/hip_runtime.h>
#include <cstdint>
#include <cstddef>

#define DEV __device__ __forceinline__

typedef _Float16 f16;
typedef __attribute__((ext_vector_type(8))) _Float16 f16x8;
typedef __attribute__((ext_vector_type(4))) float f32x4;

DEV unsigned short f2h(float f) {
  f16 h = (f16)f;
  return __builtin_bit_cast(unsigned short, h);
}

DEV void async_ld16(const void* g, void* l) {
  __builtin_amdgcn_global_load_lds(
      (__attribute__((address_space(1))) unsigned int*)(uintptr_t)g,
      (__attribute__((address_space(3))) unsigned int*)(uint32_t)(uintptr_t)l,
      16, 0, 0);
}

#define MFMA16(d, a, b_) (d) = __builtin_amdgcn_mfma_f32_16x16x32_f16((a), (b_), (d), 0, 0, 0)

// ---------------------------------------------------------------------------
// NT-GEMM: C[M x N] = A[M x K] * B[N x K]^T   (K-contiguous, f16-as-ushort)
// 128x128 tile, BK=32, 4 waves (2x2), 16x16x32 f16 MFMA, global_load_lds x16.
// EPI: 0 = fp16 store, 1 = fp32 store, 2 = fp32 atomicAdd.
// ALPHA: scale A-fragments in-loop by alphaT[ktile][row] (fp16), staged to LDS.
// ORDER: within-XCD block order: 0 = mloc-inner, 1 = rest-inner.
// Grid is 1D = nt*mt*sl; sl = split-K slices (K param = per-slice depth).
// ---------------------------------------------------------------------------
template <int BM, int BN, int EPI, bool RELU, bool HASBIAS, bool ALPHA, int ORDER>
__global__ __launch_bounds__(256) void gemm_nt(
    const unsigned short* __restrict__ A, const unsigned short* __restrict__ B,
    void* __restrict__ Cp, const float* __restrict__ bias,
    const unsigned short* __restrict__ alp, float* __restrict__ stm,
    float* __restrict__ stl, int Mtot,
    int K, int lda, int ldb, int ldc, int nt, int mt, int sl) {
  constexpr int BK = 32;
  constexpr int WM = BM / 2, WN = BN / 2;
  constexpr int FM = WM / 16, FN = WN / 16;

  __shared__ __align__(16) unsigned short As[BM * BK];
  __shared__ __align__(16) unsigned short Bs[BN * BK];
  __shared__ __align__(16) unsigned short Alds[ALPHA ? BM * 32 : 8];

  int mb, nb, zb;
  {
    const int b = blockIdx.x;
    if ((mt & 7) == 0) {
      const int xcd = b & 7;
      const int i = b >> 3;
      const int band_sz = 8 * nt * sl;
      const int band = i / band_sz;
      const int wq = i % band_sz;
      int mloc, rest;
      if (ORDER == 0) { mloc = wq & 7; rest = wq >> 3; }
      else           { rest = wq % (nt * sl); mloc = wq / (nt * sl); }
      mb = xcd + 8 * (band * 8 + mloc);
      nb = rest % nt;
      zb = rest / nt;
    } else {
      nb = b % nt;
      const int t = b / nt;
      mb = t % mt;
      zb = t / mt;
    }
  }

  const int tid = threadIdx.x;
  const int wave = tid >> 6, lane = tid & 63;
  const int wm = (wave >> 1) * WM, wn = (wave & 1) * WN;
  const int bm = mb * BM, bn = nb * BN;
  const size_t koff = (size_t)zb * K;

  const int r4 = tid >> 2;
  const int c4 = (tid & 3) * 8;

  if (ALPHA) {
    const int ntile_l = K >> 7;
    const int nu4 = (ntile_l * BM) >> 3;
    const unsigned short* g0 = alp + (size_t)(zb * ntile_l) * Mtot + bm;
    uint4* s = (uint4*)Alds;
    for (int idx = tid; idx < nu4; idx += 256) {
      const int t = idx >> 4;
      const int ru = (idx & 15) << 3;
      s[idx] = *(const uint4*)(g0 + (size_t)t * Mtot + ru);
    }
  }

  f32x4 acc[FM][FN] = {};

  const int kq = (lane >> 4) * 8;
  const int mr = lane & 15;
  const int quad = lane >> 4;

  for (int k0 = 0; k0 < K; k0 += BK) {
#pragma unroll
    for (int p = 0; p < BM / 64; ++p) {
      const unsigned short* g = A + (size_t)(bm + p * 64 + r4) * lda + koff + k0 + c4;
      async_ld16(g, &As[p * 2048 + wave * 512]);
    }
#pragma unroll
    for (int p = 0; p < BN / 64; ++p) {
      const unsigned short* g = B + (size_t)(bn + p * 64 + r4) * ldb + koff + k0 + c4;
      async_ld16(g, &Bs[p * 2048 + wave * 512]);
    }
    __syncthreads();

    f16x8 av[FM], bv[FN];
#pragma unroll
    for (int i = 0; i < FM; ++i)
      av[i] = *(const f16x8*)(const void*)&As[(wm + i * 16 + mr) * BK + kq];
#pragma unroll
    for (int j = 0; j < FN; ++j)
      bv[j] = *(const f16x8*)(const void*)&Bs[(wn + j * 16 + mr) * BK + kq];

    if (ALPHA) {
      const int tl = k0 >> 7;
#pragma unroll
      for (int i = 0; i < FM; ++i) {
        const f16 sc = ((const f16*)Alds)[tl * 128 + (wm + i * 16 + mr)];
        av[i] = av[i] * sc;
      }
    }

#pragma unroll
    for (int i = 0; i < FM; ++i)
#pragma unroll
      for (int j = 0; j < FN; ++j)
        acc[i][j] = __builtin_amdgcn_mfma_f32_16x16x32_f16(av[i], bv[j], acc[i][j], 0, 0, 0);

    __syncthreads();
  }

#pragma unroll
  for (int i = 0; i < FM; ++i) {
#pragma unroll
    for (int j = 0; j < FN; ++j) {
      const int col = bn + wn + j * 16 + mr;
      float bv_ = 0.f;
      if (HASBIAS) bv_ = bias[col];
#pragma unroll
      for (int r = 0; r < 4; ++r) {
        const int row = bm + wm + i * 16 + quad * 4 + r;
        float v = acc[i][j][r];
        if (HASBIAS) v += bv_;
        if (RELU) v = fmaxf(v, 0.f);
        if (EPI == 2)
          atomicAdd(&((float*)Cp)[(size_t)row * ldc + col], v);
        else if (EPI == 1)
          ((float*)Cp)[(size_t)row * ldc + col] = v;
        else
          ((unsigned short*)Cp)[(size_t)row * ldc + col] = f2h(v);
      }
    }
  }
}

// ---------------------------------------------------------------------------
// qk256: S = Q·K^T with fused exp + per-(row,128-col-half) m/l stats.
// 256x256 tile, BK=64, 8 waves (2Mx4N), 8-phase pipeline (HK-style):
//   per phase: {ds_read subtile | stage ONE 16KB half-tile (2x global_load_lds)
//               | s_barrier | lgkmcnt(0) | 16 MFMA (setprio) | s_barrier}
//   vmcnt(6) once per K-tile (phase 4 of 4); stage depth = 7 half-tiles.
// Ledger: half H_j consumed at phase j is staged at phase j-7; its LDS region
// was last read at phase j-8; phase (j-8)'s lgkmcnt(0)+barrier precede the
// stage issue, so no WAR race. vmcnt(6) at each tile's last phase leaves the
// 3 newest halves outstanding; everything consumed in the next 4 phases is
// older -> landed. Tail stages wrap k0 (garbage, never consumed) so the
// ledger count stays exact; vmcnt(0) before the epilogue reuses LDS.
// LDS 128KiB = 2 bufs x {A: 2 halves x [128][64], B: same} f16, XOR-swizzled:
// phys 16B-slot = logical_slot ^ (row&7); stage applies the inverse swizzle to
// the GLOBAL source (rule 21: linear LDS dest), ds_read applies it on read.
// Halves are phase-sliced: A0 = rows read in ph0 (wr*128+[0,64)), A1 = ph2's,
// B0 = ph1's (wc*64+[0,32)), B1 = ph3's -> each region read in exactly 1 phase.
// Stats layout identical to the old EPI=3 kernel (tile index = nb*2 + half),
// so combine_alpha and the PV gemm are unchanged.
// ---------------------------------------------------------------------------
__global__ __launch_bounds__(512, 2) void qk256(
    const unsigned short* __restrict__ A, const unsigned short* __restrict__ B,
    unsigned short* __restrict__ P, float* __restrict__ stm,
    float* __restrict__ stl, int M, int K, int lda, int ldb, int ldc) {
  extern __shared__ char smem[];
  const int NT = K >> 6;

  // XCD swizzle: 8 XCDs x 128 blocks, mb-inner (32 blocks share one K-panel)
  const int b = blockIdx.x;
  const int xcd = b & 7, c = b >> 3;
  const int mb = c & 31, nb = (xcd << 2) | (c >> 5);
  const int bm = mb << 8, bn = nb << 8;

  const int tid = threadIdx.x;
  const int wave = tid >> 6, lane = tid & 63;
  const int wr = wave >> 2, wc = wave & 3;   // wave grid 2 x 4
  const int mr = lane & 15, quad = lane >> 4;

  // staging: linear LDS byte L = p*8192 + tid*16 within a half;
  // row = p*64 + (tid>>3), phys slot = tid&7, logical col16 = slot ^ (row&7)
  const int slot = tid & 7, rr = tid >> 3;
  const int ce = (slot ^ (rr & 7)) << 3;     // element col offset (x8 f16)

  f32x4 acc[8][4] = {};
  f16x8 av0[4][2], av1[4][2], bv0[2][2], bv1[2][2];

  auto stA = [&](int h, int Ts) {
    const int t = Ts >= NT ? Ts - NT : Ts;   // tail wrap: keep vmcnt ledger
    const int kk = t << 6;
    char* l = smem + ((Ts & 1) << 16) + h * 16384 + wave * 1024;
#pragma unroll
    for (int p = 0; p < 2; ++p) {
      // A-half h rows: p*128 + h*64 + rr
      const unsigned off = (unsigned)(bm + p * 128 + h * 64 + rr) * (unsigned)lda + kk + ce;
      async_ld16(A + off, l + p * 8192);
    }
  };
  auto stB = [&](int h, int Ts) {
    const int t = Ts >= NT ? Ts - NT : Ts;
    const int kk = t << 6;
    char* l = smem + ((Ts & 1) << 16) + 32768 + h * 16384 + wave * 1024;
#pragma unroll
    for (int p = 0; p < 2; ++p) {
      // B-half h rows: p*128 + (rr>>5)*64 + h*32 + (rr&31)
      const unsigned off =
          (unsigned)(bn + p * 128 + (rr >> 5) * 64 + h * 32 + (rr & 31)) * (unsigned)ldb + kk + ce;
      async_ld16(B + off, l + p * 8192);
    }
  };
  auto rdA = [&](int bufc, int i, int ks) {
    const int r = wr * 64 + (i & 3) * 16 + mr;   // r&7 == mr&7
    return *(const f16x8*)(smem + bufc + (i >> 2) * 16384 + r * 128 +
                           ((((ks << 2) | quad) ^ (mr & 7)) << 4));
  };
  auto rdB = [&](int bufc, int j, int ks) {
    const int r = wc * 32 + (j & 1) * 16 + mr;
    return *(const f16x8*)(smem + bufc + 32768 + (j >> 1) * 16384 + r * 128 +
                           ((((ks << 2) | quad) ^ (mr & 7)) << 4));
  };

  // prologue: stage H0..H6 (tile0 A0,B0,A1,B1 + tile1 A0,B0,A1), wait 8 oldest
  stA(0, 0); stB(0, 0); stA(1, 0); stB(1, 0);
  stA(0, 1); stB(0, 1); stA(1, 1);
  asm volatile("s_waitcnt vmcnt(6)" ::: "memory");
  __builtin_amdgcn_s_barrier();

  for (int T = 0; T < NT; ++T) {
    const int bufc = (T & 1) << 16;
    // ---- phase 0: read A-half0 | stage B1(T+1) | MFMA prev (4..7 x 2..3)
#pragma unroll
    for (int i = 0; i < 4; ++i) { av0[i][0] = rdA(bufc, i, 0); av0[i][1] = rdA(bufc, i, 1); }
    stB(1, T + 1);
    __builtin_amdgcn_s_barrier();
    asm volatile("s_waitcnt lgkmcnt(0)" ::: "memory");
    __builtin_amdgcn_sched_barrier(0);
    if (T) {
      __builtin_amdgcn_s_setprio(1);
#pragma unroll
      for (int i = 0; i < 4; ++i)
#pragma unroll
        for (int j = 0; j < 2; ++j) {
          MFMA16(acc[4 + i][2 + j], av1[i][0], bv1[j][0]);
          MFMA16(acc[4 + i][2 + j], av1[i][1], bv1[j][1]);
        }
      __builtin_amdgcn_s_setprio(0);
    }
    __builtin_amdgcn_s_barrier();
    // ---- phase 1: read B-half0 | stage A0(T+2) | MFMA (0..3 x 0..1)
#pragma unroll
    for (int j = 0; j < 2; ++j) { bv0[j][0] = rdB(bufc, j, 0); bv0[j][1] = rdB(bufc, j, 1); }
    stA(0, T + 2);
    __builtin_amdgcn_s_barrier();
    asm volatile("s_waitcnt lgkmcnt(0)" ::: "memory");
    __builtin_amdgcn_sched_barrier(0);
    __builtin_amdgcn_s_setprio(1);
#pragma unroll
    for (int i = 0; i < 4; ++i)
#pragma unroll
      for (int j = 0; j < 2; ++j) {
        MFMA16(acc[i][j], av0[i][0], bv0[j][0]);
        MFMA16(acc[i][j], av0[i][1], bv0[j][1]);
      }
    __builtin_amdgcn_s_setprio(0);
    __builtin_amdgcn_s_barrier();
    // ---- phase 2: read A-half1 | stage B0(T+2) | MFMA (4..7 x 0..1)
#pragma unroll
    for (int i = 0; i < 4; ++i) { av1[i][0] = rdA(bufc, 4 + i, 0); av1[i][1] = rdA(bufc, 4 + i, 1); }
    stB(0, T + 2);
    __builtin_amdgcn_s_barrier();
    asm volatile("s_waitcnt lgkmcnt(0)" ::: "memory");
    __builtin_amdgcn_sched_barrier(0);
    __builtin_amdgcn_s_setprio(1);
#pragma unroll
    for (int i = 0; i < 4; ++i)
#pragma unroll
      for (int j = 0; j < 2; ++j) {
        MFMA16(acc[4 + i][j], av1[i][0], bv0[j][0]);
        MFMA16(acc[4 + i][j], av1[i][1], bv0[j][1]);
      }
    __builtin_amdgcn_s_setprio(0);
    __builtin_amdgcn_s_barrier();
    // ---- phase 3: read B-half1 | stage A1(T+2) | MFMA (0..3 x 2..3) | vmcnt(6)
#pragma unroll
    for (int j = 0; j < 2; ++j) { bv1[j][0] = rdB(bufc, 2 + j, 0); bv1[j][1] = rdB(bufc, 2 + j, 1); }
    stA(1, T + 2);
    __builtin_amdgcn_s_barrier();
    asm volatile("s_waitcnt lgkmcnt(0)" ::: "memory");
    __builtin_amdgcn_sched_barrier(0);
    __builtin_amdgcn_s_setprio(1);
#pragma unroll
    for (int i = 0; i < 4; ++i)
#pragma unroll
      for (int j = 0; j < 2; ++j) {
        MFMA16(acc[i][2 + j], av0[i][0], bv1[j][0]);
        MFMA16(acc[i][2 + j], av0[i][1], bv1[j][1]);
      }
    __builtin_amdgcn_s_setprio(0);
    asm volatile("s_waitcnt vmcnt(6)" ::: "memory");
    __builtin_amdgcn_s_barrier();
  }
  // final cross-tile cluster: (4..7 x 2..3) of tile NT-1
  __builtin_amdgcn_s_setprio(1);
#pragma unroll
  for (int i = 0; i < 4; ++i)
#pragma unroll
    for (int j = 0; j < 2; ++j) {
      MFMA16(acc[4 + i][2 + j], av1[i][0], bv1[j][0]);
      MFMA16(acc[4 + i][2 + j], av1[i][1], bv1[j][1]);
    }
  __builtin_amdgcn_s_setprio(0);
  // drain all outstanding stages before LDS reuse
  asm volatile("s_waitcnt vmcnt(0)" ::: "memory");
  __builtin_amdgcn_s_barrier();

  // ---- epilogue: exp + per-(row, 128-col-half) stats --------------------
  float* sred = (float*)smem;            // [256][4] per-wave row maxima
  float* ssum = (float*)(smem + 4096);   // [256][4] per-wave row sums
  const int hc = wc >> 1;                // this wave's 128-col half
  float Mh[8][4];

#pragma unroll
  for (int i = 0; i < 8; ++i)
#pragma unroll
    for (int r = 0; r < 4; ++r) {
      float m = acc[i][0][r];
#pragma unroll
      for (int j = 1; j < 4; ++j) m = fmaxf(m, acc[i][j][r]);
      m = fmaxf(m, __shfl_xor(m, 1));
      m = fmaxf(m, __shfl_xor(m, 2));
      m = fmaxf(m, __shfl_xor(m, 4));
      m = fmaxf(m, __shfl_xor(m, 8));
      if (mr == 0) sred[(wr * 128 + i * 16 + quad * 4 + r) * 4 + wc] = m;
    }
  __syncthreads();
#pragma unroll
  for (int i = 0; i < 8; ++i)
#pragma unroll
    for (int r = 0; r < 4; ++r) {
      const int row_l = wr * 128 + i * 16 + quad * 4 + r;
      Mh[i][r] = fmaxf(sred[row_l * 4 + 2 * hc], sred[row_l * 4 + 2 * hc + 1]);
    }
#pragma unroll
  for (int i = 0; i < 8; ++i)
#pragma unroll
    for (int r = 0; r < 4; ++r) {
      const int row_l = wr * 128 + i * 16 + quad * 4 + r;
      float l = 0.f;
#pragma unroll
      for (int j = 0; j < 4; ++j) {
        const float e = __expf(acc[i][j][r] - Mh[i][r]);
        P[(size_t)(bm + row_l) * ldc + (bn + wc * 64 + j * 16 + mr)] = f2h(e);
        l += e;
      }
      l += __shfl_xor(l, 1);
      l += __shfl_xor(l, 2);
      l += __shfl_xor(l, 4);
      l += __shfl_xor(l, 8);
      if (mr == 0) ssum[row_l * 4 + wc] = l;
    }
  __syncthreads();
  if ((wc & 1) == 0 && mr == 0) {        // waves wc=0 (half 0), wc=2 (half 1)
#pragma unroll
    for (int i = 0; i < 8; ++i)
#pragma unroll
      for (int r = 0; r < 4; ++r) {
        const int row_l = wr * 128 + i * 16 + quad * 4 + r;
        const int tile = nb * 2 + hc;    // 128-col tile index, 64 total
        stm[(size_t)tile * M + bm + row_l] = Mh[i][r];
        stl[(size_t)tile * M + bm + row_l] =
            ssum[row_l * 4 + 2 * hc] + ssum[row_l * 4 + 2 * hc + 1];
      }
  }
}

// per-row combine: M = max_t m_t, L = sum_t l_t*exp(m_t-M)
// writes alpha TRANSPOSED: alp[tile * Mtot + row] = exp(m_t - M) / L
__global__ __launch_bounds__(256) void combine_alpha(
    const float* __restrict__ stm, const float* __restrict__ stl,
    unsigned short* __restrict__ alp, int ntile, int Mtot) {
  const int row = blockIdx.x * 4 + (threadIdx.x >> 6);
  const int t = threadIdx.x & 63;
  float m = (t < ntile) ? stm[(size_t)t * Mtot + row] : -1e30f;
  float M = m;
#pragma unroll
  for (int o = 1; o < 64; o <<= 1) M = fmaxf(M, __shfl_xor(M, o));
  float l = (t < ntile) ? stl[(size_t)t * Mtot + row] : 0.f;
  float c = l * __expf(m - M);
#pragma unroll
  for (int o = 1; o < 64; o <<= 1) c += __shfl_xor(c, o);
  if (t < ntile) alp[(size_t)t * Mtot + row] = f2h(__expf(m - M) / c);
}

__global__ __launch_bounds__(256) void cvt_f16(const float* __restrict__ in,
                                               unsigned short* __restrict__ out, int n) {
  int i = blockIdx.x * 256 + threadIdx.x;
  if (i < n) out[i] = f2h(in[i]);
}

__global__ __launch_bounds__(256) void bias_fill(float* __restrict__ out,
                                                 const float* __restrict__ b, int d) {
  int i = blockIdx.x * 256 + threadIdx.x;
  out[i] = b[i % d];
}

// V [8192 x 768] fp32 -> vT [768 x 8192] fp16
__global__ __launch_bounds__(256) void vt_kernel(const float* __restrict__ V,
                                                 unsigned short* __restrict__ vT) {
  __shared__ float t[32][33];
  const int bx = blockIdx.x, by = blockIdx.y;
  const int x = threadIdx.x, y = threadIdx.y;  // (32, 8)
#pragma unroll
  for (int r = 0; r < 4; ++r)
    t[y + r * 8][x] = V[(size_t)(by * 32 + y + r * 8) * 768 + bx * 32 + x];
  __syncthreads();
#pragma unroll
  for (int r = 0; r < 4; ++r)
    vT[(size_t)(bx * 32 + y + r * 8) * 8192 + by * 32 + x] = f2h(t[x][y + r * 8]);
}

// ---------------------------------------------------------------------------
extern "C" void kernel_launch(void* const* d_in, const int* in_sizes, int n_in,
                              void* d_out, int out_size, void* d_ws, size_t ws_size,
                              hipStream_t stream) {
  const int N = 8192, D = 768, DFF = 2048;
  const float* Q  = (const float*)d_in[0];
  const float* Km = (const float*)d_in[1];
  const float* V  = (const float*)d_in[2];
  const float* W1 = (const float*)d_in[3];
  const float* b1 = (const float*)d_in[4];
  const float* W2 = (const float*)d_in[5];
  const float* b2 = (const float*)d_in[6];

  char* w = (char*)d_ws;
  size_t off = 0;
  auto take = [&](size_t bytes) { void* p = w + off; off += bytes; return p; };
  unsigned short* qh   = (unsigned short*)take((size_t)N * D * 2);
  unsigned short* kh   = (unsigned short*)take((size_t)N * D * 2);
  unsigned short* vT   = (unsigned short*)take((size_t)N * D * 2);
  unsigned short* ctx16= (unsigned short*)take((size_t)N * D * 2);
  float*          ctx32= (float*)take((size_t)N * D * 4);
  unsigned short* hb   = (unsigned short*)take((size_t)N * DFF * 2);
  unsigned short* w1h  = (unsigned short*)take((size_t)DFF * D * 2);
  unsigned short* w2h  = (unsigned short*)take((size_t)D * DFF * 2);
  float*          stm  = (float*)take((size_t)64 * N * 4);
  float*          stl  = (float*)take((size_t)64 * N * 4);
  unsigned short* alp  = (unsigned short*)take((size_t)64 * N * 2);  // [tile][row]
  unsigned short* Pp   = (unsigned short*)take((size_t)N * N * 2);   // P' fp16, 128 MB
  (void)ws_size;

  cvt_f16<<<(N * D) / 256, 256, 0, stream>>>(Q, qh, N * D);
  cvt_f16<<<(N * D) / 256, 256, 0, stream>>>(Km, kh, N * D);
  vt_kernel<<<dim3(D / 32, N / 32), dim3(32, 8), 0, stream>>>(V, vT);
  cvt_f16<<<(DFF * D) / 256, 256, 0, stream>>>(W1, w1h, DFF * D);
  cvt_f16<<<(D * DFF) / 256, 256, 0, stream>>>(W2, w2h, D * DFF);
  hipMemsetAsync(ctx32, 0, (size_t)N * D * 4, stream);
  bias_fill<<<(N * D) / 256, 256, 0, stream>>>((float*)d_out, b2, D);

  {  // QK^T 256^2 8-phase with fused exp + per-(row,128-tile) stats
    hipFuncSetAttribute((const void*)qk256,
                        hipFuncAttributeMaxDynamicSharedMemorySize, 131072);
    qk256<<<(N / 256) * (N / 256), 512, 131072, stream>>>(
        qh, kh, Pp, stm, stl, N, D, D, D, N);
  }
  combine_alpha<<<N / 4, 256, 0, stream>>>(stm, stl, alp, 64, N);
  {  // ctx32 += (alphaT .* P') . V  — split-K sl=2, fp32 atomics
    const int nt = D / 128, mt = N / 128, sl = 2;
    gemm_nt<128, 128, 2, false, false, true, 1>
        <<<nt * mt * sl, 256, 0, stream>>>(
            Pp, vT, ctx32, nullptr, alp, nullptr, nullptr, N,
            N / sl, N, N, D, nt, mt, sl);
  }
  cvt_f16<<<(N * D) / 256, 256, 0, stream>>>(ctx32, ctx16, N * D);

  {  // h = relu(ctx . W1^T + b1)  fp16
    const int nt = DFF / 128, mt = N / 128;
    gemm_nt<128, 128, 0, true, true, false, 1>
        <<<nt * mt, 256, 0, stream>>>(
            ctx16, w1h, hb, b1, nullptr, nullptr, nullptr, N,
            D, D, D, DFF, nt, mt, 1);
  }
  {  // out += h . W2^T  (bias pre-filled) — split-K sl=2, fp32 atomics
    const int nt = D / 128, mt = N / 128, sl = 2;
    gemm_nt<128, 128, 2, false, false, false, 1>
        <<<nt * mt * sl, 256, 0, stream>>>(
            hb, w2h, (float*)d_out, nullptr, nullptr, nullptr, nullptr, N,
            DFF / sl, DFF, DFF, D, nt, mt, sl);
  }
}